// Round 2
// baseline (4400.962 us; speedup 1.0000x reference)
//
#include <hip/hip_runtime.h>
#include <cstdint>
#include <cstddef>

// VQ nearest-codebook: replicate numpy fp32 pipeline bitwise.
// d2 = fl(fl(zsq - 2*dot) + csq), dot = fl(S(0:384)+S(384:512)) seq fp32 FMA,
// zsq = np pairwise fp32 (AVX512 npyv tree), argmin ties -> lowest index.
constexpr int N_ROWS = 32768;
constexpr int KC     = 8192;
constexpr int DIMS   = 512;

constexpr int BM = 128, BN = 128, BK = 32;
constexpr int LDA = BM + 4, LDB = BN + 4;
constexpr int KSPLIT_TILE = 11;  // after kt==11 (k=384) start 2nd BLAS kc-panel

// ---- csq: any summation order (error ~1e-12 << bin 3e-5) ----
__global__ __launch_bounds__(256) void csq_kernel(const float* __restrict__ cb,
                                                  float* __restrict__ csq) {
  int gid  = blockIdx.x * blockDim.x + threadIdx.x;
  int code = gid >> 6;
  int lane = threadIdx.x & 63;
  const float4* row = (const float4*)(cb + (size_t)code * DIMS);
  float4 a = row[lane];
  float4 b = row[lane + 64];
  float s = a.x*a.x + a.y*a.y + a.z*a.z + a.w*a.w
          + b.x*b.x + b.y*b.y + b.z*b.z + b.w*b.w;
  #pragma unroll
  for (int off = 32; off > 0; off >>= 1) s += __shfl_down(s, off, 64);
  if (lane == 0) csq[code] = s;
}

// ---- zsq: bitwise replica of np.sum(z*z,-1) fp32 pairwise, AVX512 npyv ----
// 512 = 4 blocks of 128. Block: r[j][l]=fl(z^2)[16j+l]; u_l=((r0+r1)+(r2+r3))
// +((r4+r5)+(r6+r7)); hsum16 strided halving (8,4,2,1). Final (B0+B1)+(B2+B3).
__global__ __launch_bounds__(256) void zsq_kernel(const float* __restrict__ z,
                                                  float* __restrict__ zsq) {
  int row  = (blockIdx.x * 256 + threadIdx.x) >> 6;  // one row per wave
  int lane = threadIdx.x & 63;
  int blk = lane >> 4, l16 = lane & 15;
  const float* p = z + (size_t)row * DIMS + blk * 128 + l16;
  float A[8];
  #pragma unroll
  for (int j = 0; j < 8; ++j) { float v = p[16 * j]; A[j] = __fmul_rn(v, v); }
  float u = __fadd_rn(__fadd_rn(__fadd_rn(A[0], A[1]), __fadd_rn(A[2], A[3])),
                      __fadd_rn(__fadd_rn(A[4], A[5]), __fadd_rn(A[6], A[7])));
  u = __fadd_rn(u, __shfl_xor(u, 8, 64));   // _mm512_reduce_add_ps halving
  u = __fadd_rn(u, __shfl_xor(u, 4, 64));
  u = __fadd_rn(u, __shfl_xor(u, 2, 64));
  u = __fadd_rn(u, __shfl_xor(u, 1, 64));   // B_blk in all 16 lanes of group
  u = __fadd_rn(u, __shfl_xor(u, 16, 64));  // B0+B1 | B2+B3
  u = __fadd_rn(u, __shfl_xor(u, 32, 64));  // (B0+B1)+(B2+B3)
  if (lane == 0) zsq[row] = u;
}

__global__ __launch_bounds__(256) void vq_argmin_kernel(
    const float* __restrict__ z, const float* __restrict__ cb,
    const float* __restrict__ csq, const float* __restrict__ zsq,
    float* __restrict__ zq, float* __restrict__ idx_out) {
  __shared__ float As[BK * LDA];
  __shared__ float Bs[BK * LDB];
  __shared__ float rs[BM * 16];
  __shared__ int   ri[BM * 16];
  __shared__ int   rowidx[BM];

  const int tid = threadIdx.x;
  const int tx  = tid & 15;
  const int ty  = tid >> 4;
  const int m0  = blockIdx.x * BM;

  float zs[8];
  #pragma unroll
  for (int i = 0; i < 8; ++i) zs[i] = zsq[m0 + ty * 8 + i];

  float best[8];
  int   bidx[8];
  #pragma unroll
  for (int i = 0; i < 8; ++i) { best[i] = INFINITY; bidx[i] = 0; }

  for (int nt = 0; nt < KC; nt += BN) {
    float acc[8][8];   // current kc-panel accumulator (sequential FMA chain)
    float accA[8][8];  // finished first panel S(0:384)
    #pragma unroll
    for (int i = 0; i < 8; ++i)
      #pragma unroll
      for (int j = 0; j < 8; ++j) { acc[i][j] = 0.f; accA[i][j] = 0.f; }

    for (int kt = 0; kt < DIMS / BK; ++kt) {
      int k0 = kt * BK;
      #pragma unroll
      for (int q = 0; q < 4; ++q) {
        int f   = q * 256 + tid;
        int row = f >> 3;
        int kq  = (f & 7) * 4;
        float4 av = *(const float4*)(z  + (size_t)(m0 + row) * DIMS + k0 + kq);
        As[(kq + 0) * LDA + row] = av.x;
        As[(kq + 1) * LDA + row] = av.y;
        As[(kq + 2) * LDA + row] = av.z;
        As[(kq + 3) * LDA + row] = av.w;
        float4 bv = *(const float4*)(cb + (size_t)(nt + row) * DIMS + k0 + kq);
        Bs[(kq + 0) * LDB + row] = bv.x;
        Bs[(kq + 1) * LDB + row] = bv.y;
        Bs[(kq + 2) * LDB + row] = bv.z;
        Bs[(kq + 3) * LDB + row] = bv.w;
      }
      __syncthreads();
      #pragma unroll
      for (int kk = 0; kk < BK; ++kk) {
        float4 a0 = *(const float4*)&As[kk * LDA + ty * 8];
        float4 a1 = *(const float4*)&As[kk * LDA + ty * 8 + 4];
        float4 b0 = *(const float4*)&Bs[kk * LDB + tx * 8];
        float4 b1 = *(const float4*)&Bs[kk * LDB + tx * 8 + 4];
        float a[8] = {a0.x, a0.y, a0.z, a0.w, a1.x, a1.y, a1.z, a1.w};
        float b[8] = {b0.x, b0.y, b0.z, b0.w, b1.x, b1.y, b1.z, b1.w};
        #pragma unroll
        for (int i = 0; i < 8; ++i)
          #pragma unroll
          for (int j = 0; j < 8; ++j)
            acc[i][j] = __fmaf_rn(a[i], b[j], acc[i][j]);
      }
      __syncthreads();
      if (kt == KSPLIT_TILE) {  // close first BLAS kc-panel (k=0..383)
        #pragma unroll
        for (int i = 0; i < 8; ++i)
          #pragma unroll
          for (int j = 0; j < 8; ++j) { accA[i][j] = acc[i][j]; acc[i][j] = 0.f; }
      }
    }

    // d2 = fl(fl(zsq - 2*dot) + csq); ascending codes + strict < = first-min
    #pragma unroll
    for (int j = 0; j < 8; ++j) {
      int   code = nt + tx * 8 + j;
      float cs   = csq[code];
      #pragma unroll
      for (int i = 0; i < 8; ++i) {
        float cross = __fadd_rn(accA[i][j], acc[i][j]);  // fl(S1 + S2)
        float t     = __fmaf_rn(-2.f, cross, zs[i]);     // fl(zsq - 2*cross)
        float q     = __fadd_rn(t, cs);                  // fl(t + csq)
        if (q < best[i]) { best[i] = q; bidx[i] = code; }
      }
    }
  }

  #pragma unroll
  for (int i = 0; i < 8; ++i) {
    int r = ty * 8 + i;
    rs[r * 16 + tx] = best[i];
    ri[r * 16 + tx] = bidx[i];
  }
  __syncthreads();
  if (tid < BM) {
    float bs = rs[tid * 16];
    int   bi = ri[tid * 16];
    #pragma unroll
    for (int t = 1; t < 16; ++t) {
      float s  = rs[tid * 16 + t];
      int   ix = ri[tid * 16 + t];
      if (s < bs || (s == bs && ix < bi)) { bs = s; bi = ix; }
    }
    idx_out[m0 + tid] = (float)bi;
    rowidx[tid] = bi;
  }
  __syncthreads();

  const float4* cb4 = (const float4*)cb;
  float4*       zq4 = (float4*)zq;
  for (int q = tid; q < BM * (DIMS / 4); q += 256) {
    int r = q >> 7;
    int c = q & 127;
    zq4[(size_t)(m0 + r) * (DIMS / 4) + c] =
        cb4[(size_t)rowidx[r] * (DIMS / 4) + c];
  }
}

extern "C" void kernel_launch(void* const* d_in, const int* in_sizes, int n_in,
                              void* d_out, int out_size, void* d_ws, size_t ws_size,
                              hipStream_t stream) {
  const float* z  = (const float*)d_in[0];
  const float* cb = (const float*)d_in[1];
  float* out     = (float*)d_out;
  float* zq      = out;
  float* idx_out = out + (size_t)N_ROWS * DIMS;
  float* csq = (float*)d_ws;          // KC floats
  float* zsq = (float*)d_ws + KC;     // N_ROWS floats

  csq_kernel<<<KC / 4, 256, 0, stream>>>(cb, csq);
  zsq_kernel<<<N_ROWS / 4, 256, 0, stream>>>(z, zsq);
  vq_argmin_kernel<<<N_ROWS / BM, 256, 0, stream>>>(z, cb, csq, zsq, zq, idx_out);
}

// Round 3
// 4252.824 us; speedup vs baseline: 1.0348x; 1.0348x over previous
//
#include <hip/hip_runtime.h>
#include <cstdint>
#include <cstddef>

// VQ nearest-codebook: replicate numpy fp32 pipeline bitwise.
// d2 = fl(fl(zsq - 2*dot) + csq), dot = fl(S(0:384)+S(384:512)) seq fp32 FMA,
// zsq = np pairwise fp32 (AVX512 npyv tree), argmin ties -> lowest index.
// R3: KC split across 2 blocks (2 blocks/CU co-residency) + 2-way b-read map.
constexpr int N_ROWS = 32768;
constexpr int KC     = 8192;
constexpr int DIMS   = 512;

constexpr int BM = 128, BN = 128, BK = 32;
constexpr int LDA = BM + 4, LDB = BN + 4;
constexpr int KSPLIT_TILE = 11;  // after kt==11 (k=384) start 2nd BLAS kc-panel

// ---- csq: any summation order (error ~1e-12 << bin 3e-5) ----
__global__ __launch_bounds__(256) void csq_kernel(const float* __restrict__ cb,
                                                  float* __restrict__ csq) {
  int gid  = blockIdx.x * blockDim.x + threadIdx.x;
  int code = gid >> 6;
  int lane = threadIdx.x & 63;
  const float4* row = (const float4*)(cb + (size_t)code * DIMS);
  float4 a = row[lane];
  float4 b = row[lane + 64];
  float s = a.x*a.x + a.y*a.y + a.z*a.z + a.w*a.w
          + b.x*b.x + b.y*b.y + b.z*b.z + b.w*b.w;
  #pragma unroll
  for (int off = 32; off > 0; off >>= 1) s += __shfl_down(s, off, 64);
  if (lane == 0) csq[code] = s;
}

// ---- zsq: bitwise replica of np.sum(z*z,-1) fp32 pairwise, AVX512 npyv ----
__global__ __launch_bounds__(256) void zsq_kernel(const float* __restrict__ z,
                                                  float* __restrict__ zsq) {
  int row  = (blockIdx.x * 256 + threadIdx.x) >> 6;  // one row per wave
  int lane = threadIdx.x & 63;
  int blk = lane >> 4, l16 = lane & 15;
  const float* p = z + (size_t)row * DIMS + blk * 128 + l16;
  float A[8];
  #pragma unroll
  for (int j = 0; j < 8; ++j) { float v = p[16 * j]; A[j] = __fmul_rn(v, v); }
  float u = __fadd_rn(__fadd_rn(__fadd_rn(A[0], A[1]), __fadd_rn(A[2], A[3])),
                      __fadd_rn(__fadd_rn(A[4], A[5]), __fadd_rn(A[6], A[7])));
  u = __fadd_rn(u, __shfl_xor(u, 8, 64));
  u = __fadd_rn(u, __shfl_xor(u, 4, 64));
  u = __fadd_rn(u, __shfl_xor(u, 2, 64));
  u = __fadd_rn(u, __shfl_xor(u, 1, 64));
  u = __fadd_rn(u, __shfl_xor(u, 16, 64));
  u = __fadd_rn(u, __shfl_xor(u, 32, 64));
  if (lane == 0) zsq[row] = u;
}

// grid = 512: blockIdx = rowTile*2 + half; each block scans 4096 codes.
__global__ __launch_bounds__(256) void vq_argmin_kernel(
    const float* __restrict__ z, const float* __restrict__ cb,
    const float* __restrict__ csq, const float* __restrict__ zsq,
    float* __restrict__ sc_out, int* __restrict__ bi_out) {
  __shared__ float As[BK * LDA];
  __shared__ float Bs[BK * LDB];
  __shared__ float rs[BM * 16];
  __shared__ int   ri[BM * 16];

  const int tid  = threadIdx.x;
  const int tx   = tid & 15;
  const int ty   = tid >> 4;
  const int half = blockIdx.x & 1;
  const int m0   = (blockIdx.x >> 1) * BM;
  const int nt0  = half * (KC / 2);

  float zs[8];
  #pragma unroll
  for (int i = 0; i < 8; ++i) zs[i] = zsq[m0 + ty * 8 + i];

  float best[8];
  int   bidx[8];
  #pragma unroll
  for (int i = 0; i < 8; ++i) { best[i] = INFINITY; bidx[i] = 0; }

  for (int nt = nt0; nt < nt0 + KC / 2; nt += BN) {
    float acc[8][8];   // current kc-panel accumulator (sequential FMA chain)
    float accA[8][8];  // finished first panel S(0:384)
    #pragma unroll
    for (int i = 0; i < 8; ++i)
      #pragma unroll
      for (int j = 0; j < 8; ++j) { acc[i][j] = 0.f; accA[i][j] = 0.f; }

    for (int kt = 0; kt < DIMS / BK; ++kt) {
      int k0 = kt * BK;
      #pragma unroll
      for (int q = 0; q < 4; ++q) {
        int f   = q * 256 + tid;
        int row = f >> 3;
        int kq  = (f & 7) * 4;
        float4 av = *(const float4*)(z  + (size_t)(m0 + row) * DIMS + k0 + kq);
        As[(kq + 0) * LDA + row] = av.x;
        As[(kq + 1) * LDA + row] = av.y;
        As[(kq + 2) * LDA + row] = av.z;
        As[(kq + 3) * LDA + row] = av.w;
        float4 bv = *(const float4*)(cb + (size_t)(nt + row) * DIMS + k0 + kq);
        Bs[(kq + 0) * LDB + row] = bv.x;
        Bs[(kq + 1) * LDB + row] = bv.y;
        Bs[(kq + 2) * LDB + row] = bv.z;
        Bs[(kq + 3) * LDB + row] = bv.w;
      }
      __syncthreads();
      #pragma unroll
      for (int kk = 0; kk < BK; ++kk) {
        float4 a0 = *(const float4*)&As[kk * LDA + ty * 8];
        float4 a1 = *(const float4*)&As[kk * LDA + ty * 8 + 4];
        // 2-way bank map: cols tx*4 and 64+tx*4 (stride-4 => free 2-way)
        float4 b0 = *(const float4*)&Bs[kk * LDB + tx * 4];
        float4 b1 = *(const float4*)&Bs[kk * LDB + 64 + tx * 4];
        float a[8] = {a0.x, a0.y, a0.z, a0.w, a1.x, a1.y, a1.z, a1.w};
        float b[8] = {b0.x, b0.y, b0.z, b0.w, b1.x, b1.y, b1.z, b1.w};
        #pragma unroll
        for (int i = 0; i < 8; ++i)
          #pragma unroll
          for (int j = 0; j < 8; ++j)
            acc[i][j] = __fmaf_rn(a[i], b[j], acc[i][j]);
      }
      __syncthreads();
      if (kt == KSPLIT_TILE) {  // close first BLAS kc-panel (k=0..383)
        #pragma unroll
        for (int i = 0; i < 8; ++i)
          #pragma unroll
          for (int j = 0; j < 8; ++j) { accA[i][j] = acc[i][j]; acc[i][j] = 0.f; }
      }
    }

    // d2 = fl(fl(zsq - 2*dot) + csq); ascending codes + strict < = first-min
    #pragma unroll
    for (int j = 0; j < 8; ++j) {
      int   code = nt + ((j >> 2) << 6) + tx * 4 + (j & 3);
      float cs   = csq[code];
      #pragma unroll
      for (int i = 0; i < 8; ++i) {
        float cross = __fadd_rn(accA[i][j], acc[i][j]);  // fl(S1 + S2)
        float t     = __fmaf_rn(-2.f, cross, zs[i]);     // fl(zsq - 2*cross)
        float q     = __fadd_rn(t, cs);                  // fl(t + csq)
        if (q < best[i]) { best[i] = q; bidx[i] = code; }
      }
    }
  }

  #pragma unroll
  for (int i = 0; i < 8; ++i) {
    int r = ty * 8 + i;
    rs[r * 16 + tx] = best[i];
    ri[r * 16 + tx] = bidx[i];
  }
  __syncthreads();
  if (tid < BM) {
    float bs = rs[tid * 16];
    int   bi = ri[tid * 16];
    #pragma unroll
    for (int t = 1; t < 16; ++t) {
      float s  = rs[tid * 16 + t];
      int   ix = ri[tid * 16 + t];
      if (s < bs || (s == bs && ix < bi)) { bs = s; bi = ix; }
    }
    sc_out[half * N_ROWS + m0 + tid] = bs;
    bi_out[half * N_ROWS + m0 + tid] = bi;
  }
}

// merge the two half-argmins (half0 wins ties: all its codes are lower) + gather
__global__ __launch_bounds__(256) void combine_gather_kernel(
    const float* __restrict__ sc, const int* __restrict__ bi,
    const float* __restrict__ cb, float* __restrict__ zq,
    float* __restrict__ idx_out) {
  int row  = blockIdx.x * 4 + (threadIdx.x >> 6);
  int lane = threadIdx.x & 63;
  float s0 = sc[row], s1 = sc[N_ROWS + row];
  int   i0 = bi[row], i1 = bi[N_ROWS + row];
  int pick = (s1 < s0) ? i1 : i0;
  if (lane == 0) idx_out[row] = (float)pick;
  const float4* cb4 = (const float4*)cb;
  float4*       zq4 = (float4*)zq;
  zq4[(size_t)row * 128 + lane]      = cb4[(size_t)pick * 128 + lane];
  zq4[(size_t)row * 128 + 64 + lane] = cb4[(size_t)pick * 128 + 64 + lane];
}

extern "C" void kernel_launch(void* const* d_in, const int* in_sizes, int n_in,
                              void* d_out, int out_size, void* d_ws, size_t ws_size,
                              hipStream_t stream) {
  const float* z  = (const float*)d_in[0];
  const float* cb = (const float*)d_in[1];
  float* out     = (float*)d_out;
  float* zq      = out;
  float* idx_out = out + (size_t)N_ROWS * DIMS;
  float* csq = (float*)d_ws;                       // KC floats
  float* zsq = csq + KC;                           // N_ROWS floats
  float* sc  = zsq + N_ROWS;                       // 2*N_ROWS floats
  int*   bi  = (int*)(sc + 2 * N_ROWS);            // 2*N_ROWS ints

  csq_kernel<<<KC / 4, 256, 0, stream>>>(cb, csq);
  zsq_kernel<<<N_ROWS / 4, 256, 0, stream>>>(z, zsq);
  vq_argmin_kernel<<<(N_ROWS / BM) * 2, 256, 0, stream>>>(z, cb, csq, zsq, sc, bi);
  combine_gather_kernel<<<N_ROWS / 4, 256, 0, stream>>>(sc, bi, cb, zq, idx_out);
}